// Round 6
// baseline (385.800 us; speedup 1.0000x reference)
//
#include <hip/hip_runtime.h>

typedef unsigned short ushort_t;
typedef __bf16 bf16x8 __attribute__((ext_vector_type(8)));
typedef float f32x4 __attribute__((ext_vector_type(4)));
typedef short short8 __attribute__((ext_vector_type(8)));

#define SBAR()   __builtin_amdgcn_s_barrier()
#define WAITV4() asm volatile("s_waitcnt vmcnt(4)" ::: "memory")

__device__ __forceinline__ float bf2f(unsigned short u) {
    union { unsigned int i; float f; } v; v.i = ((unsigned int)u) << 16; return v.f;
}
__device__ __forceinline__ unsigned short f2bf(float f) {
    union { float f; unsigned int i; } v; v.f = f;
    unsigned int r = v.i + 0x7fffu + ((v.i >> 16) & 1u);
    return (unsigned short)(r >> 16);
}
__device__ __forceinline__ float sigm(float x) { return 1.0f / (1.0f + __expf(-x)); }

__device__ __forceinline__ void async_copy16(const ushort_t* src, ushort_t* dst_lds) {
    __builtin_amdgcn_global_load_lds(
        (const __attribute__((address_space(1))) void*)src,
        (__attribute__((address_space(3))) void*)dst_lds,
        16, 0, 0);
}

__device__ __forceinline__ f32x4 MFMA(bf16x8 a, bf16x8 b, f32x4 c) {
    return __builtin_amdgcn_mfma_f32_16x16x32_bf16(a, b, c, 0, 0, 0);
}

// ---- param conversion: 5 W (768x768) + 5 bias (768) + ts (768), f32 -> bf16 ----
#define WSEG 589824           // 768*768
#define NWALL 2949120         // 5*WSEG
#define NTOT 2953728          // + 6*768
__global__ __launch_bounds__(256)
void convert_params(const float* __restrict__ Wq, const float* __restrict__ Wk,
                    const float* __restrict__ Wv, const float* __restrict__ Wg1,
                    const float* __restrict__ Wg2, const float* __restrict__ bq,
                    const float* __restrict__ bk, const float* __restrict__ bv,
                    const float* __restrict__ bg1, const float* __restrict__ bg2,
                    const float* __restrict__ ts, ushort_t* __restrict__ dst)
{
    int i = (blockIdx.x * 256 + threadIdx.x) * 8;
    if (i >= NTOT) return;
    const float* src; int off;
    if (i < NWALL) {
        int wi = i / WSEG; off = i - wi * WSEG;
        src = (wi == 0) ? Wq : (wi == 1) ? Wk : (wi == 2) ? Wv : (wi == 3) ? Wg1 : Wg2;
    } else {
        int j = i - NWALL; int bi = j / 768; off = j - bi * 768;
        src = (bi == 0) ? bq : (bi == 1) ? bk : (bi == 2) ? bv : (bi == 3) ? bg1 : (bi == 4) ? bg2 : ts;
    }
    float4 a = *(const float4*)(src + off);
    float4 b = *(const float4*)(src + off + 4);
    short8 o;
    o[0] = (short)f2bf(a.x); o[1] = (short)f2bf(a.y); o[2] = (short)f2bf(a.z); o[3] = (short)f2bf(a.w);
    o[4] = (short)f2bf(b.x); o[5] = (short)f2bf(b.y); o[6] = (short)f2bf(b.z); o[7] = (short)f2bf(b.w);
    *(short8*)(dst + i) = o;
}

// ---- input conversion: query/key/value [16384x768] f32 -> bf16 into X[3] ----
#define PERT 12582912ll
__global__ __launch_bounds__(256)
void convert_inputs(const float* __restrict__ q, const float* __restrict__ k,
                    const float* __restrict__ v, ushort_t* __restrict__ X)
{
    long long i = ((long long)blockIdx.x * 256 + threadIdx.x) * 8;
    const float* src; long long off;
    if (i < PERT)          { src = q; off = i; }
    else if (i < 2 * PERT) { src = k; off = i - PERT; }
    else                   { src = v; off = i - 2 * PERT; }
    float4 a = *(const float4*)(src + off);
    float4 b = *(const float4*)(src + off + 4);
    short8 o;
    o[0] = (short)f2bf(a.x); o[1] = (short)f2bf(a.y); o[2] = (short)f2bf(a.z); o[3] = (short)f2bf(a.w);
    o[4] = (short)f2bf(b.x); o[5] = (short)f2bf(b.y); o[6] = (short)f2bf(b.z); o[7] = (short)f2bf(b.w);
    *(short8*)(X + i) = o;
}

// ---- 256x256 8-phase GEMM: C[M,N] = A[M,K] @ B[N,K]^T, bf16, batched ----
// LDS: 2 dbuf x 2 halves x [128][64] for A and B (128 KiB). Slot swizzle: phys = slot ^ (row&7).
// Phase: {ds-read frags; stage 1 half (2x gload_lds); [vmcnt(4) @P4/P8]; barrier; 16 MFMA; barrier}
template<int NOFF>
__device__ __forceinline__ void load_b2(bf16x8 (&bF)[4][2], const ushort_t* Bh, int rbase,
                                        int l15, int k4, int l7)
{
    #pragma unroll
    for (int n = 0; n < 2; ++n) {
        const int row = rbase + (NOFF + n) * 16 + l15;
        bF[NOFF + n][0] = *(const bf16x8*)(Bh + (row << 6) + (((0 + k4) ^ l7) << 3));
        bF[NOFF + n][1] = *(const bf16x8*)(Bh + (row << 6) + (((4 + k4) ^ l7) << 3));
    }
}
__device__ __forceinline__ void load_a4(bf16x8 (&aF)[4][2], const ushort_t* Ah, int moff,
                                        int l15, int k4, int l7)
{
    #pragma unroll
    for (int m = 0; m < 4; ++m) {
        const int row = (moff + m) * 16 + l15;
        aF[m][0] = *(const bf16x8*)(Ah + (row << 6) + (((0 + k4) ^ l7) << 3));
        aF[m][1] = *(const bf16x8*)(Ah + (row << 6) + (((4 + k4) ^ l7) << 3));
    }
}
template<int MB, int NB>
__device__ __forceinline__ void mfma16(f32x4 (&acc)[8][4], const bf16x8 (&aF)[4][2],
                                       const bf16x8 (&bF)[4][2])
{
    __builtin_amdgcn_s_setprio(1);
    #pragma unroll
    for (int m = 0; m < 4; ++m)
        #pragma unroll
        for (int n = 0; n < 2; ++n) {
            acc[MB + m][NB + n] = MFMA(aF[m][0], bF[NB + n][0], acc[MB + m][NB + n]);
            acc[MB + m][NB + n] = MFMA(aF[m][1], bF[NB + n][1], acc[MB + m][NB + n]);
        }
    __builtin_amdgcn_s_setprio(0);
}

// EPI: 0=plain, 1=+bias (bias + bz*768; C2 used when bz==2), 2=*scale, 3=+bias+relu,
//      4=gate sigmoid(sigmoid(x+bias))*aux*ts (CF32 out)
template<int EPI, int CF32>
__global__ __launch_bounds__(512, 1)
void gemm256(const ushort_t* __restrict__ A, const ushort_t* __restrict__ B,
             void* __restrict__ Cv, void* __restrict__ Cv2,
             const ushort_t* __restrict__ bias,
             const ushort_t* __restrict__ aux, const ushort_t* __restrict__ ts,
             int M, int N, int K, float scale,
             long long batchA, long long batchB, long long batchC)
{
    __shared__ __align__(16) ushort_t As[2][2][8192];
    __shared__ __align__(16) ushort_t Bs[2][2][8192];
    const int tid  = threadIdx.x;
    const int lane = tid & 63;
    const int wid  = tid >> 6;
    const int wr = wid >> 2;          // 0..1 -> A half
    const int wc = wid & 3;           // 0..3 -> B half = wc>>1, sub = wc&1
    const int l15 = lane & 15, k4 = lane >> 4, l7 = lane & 7;

    // XCD-aware bijective swizzle (nwg % 8 == 0)
    const int gx = gridDim.x, gy = gridDim.y;
    const int nwg = gx * gy * gridDim.z;
    int fid = (blockIdx.z * gy + blockIdx.y) * gx + blockIdx.x;
    fid = (fid & 7) * (nwg >> 3) + (fid >> 3);
    const int bz  = fid / (gx * gy);
    const int rem = fid - bz * (gx * gy);
    const int by  = rem / gx;
    const int bx  = rem - by * gx;
    const int row0 = by * 256;
    const int col0 = bx * 256;

    const ushort_t* Ab = A + batchA * bz;
    const ushort_t* Bb = B + batchB * bz;

    // staging: thread t -> row t>>3 (0..63), phys slot t&7; global slot pre-swizzled
    const int srow  = tid >> 3;
    const int sslot = (tid & 7) ^ (srow & 7);
    const ushort_t* aB0 = Ab + (size_t)(row0 + srow) * K + sslot * 8;
    const ushort_t* aB1 = aB0 + (size_t)128 * K;
    const ushort_t* bB0 = Bb + (size_t)(col0 + srow) * K + sslot * 8;
    const ushort_t* bB1 = bB0 + (size_t)128 * K;

    ushort_t* A00 = &As[0][0][0]; ushort_t* A01 = &As[0][1][0];
    ushort_t* A10 = &As[1][0][0]; ushort_t* A11 = &As[1][1][0];
    ushort_t* B00 = &Bs[0][0][0]; ushort_t* B01 = &Bs[0][1][0];
    ushort_t* B10 = &Bs[1][0][0]; ushort_t* B11 = &Bs[1][1][0];

#define STAGE(G, L) do { \
    async_copy16((G), (L) + tid * 8); \
    async_copy16((G) + (size_t)64 * K, (L) + 4096 + tid * 8); \
} while (0)

    const ushort_t* Ah0 = &As[0][wr][0];
    const ushort_t* Ah1 = &As[1][wr][0];
    const ushort_t* Bh0 = &Bs[0][wc >> 1][0];
    const ushort_t* Bh1 = &Bs[1][wc >> 1][0];
    const int brbase = (wc & 1) * 64;

    f32x4 acc[8][4] = {};
    bf16x8 aF[4][2], bF[4][2];

    const int NT  = K >> 6;    // 64-wide K tiles (even, >=2)
    const int NT2 = NT >> 1;

    // prologue: buf0 <- tile0 (B halves then A halves), buf1.B <- tile1
    STAGE(bB0, B00); STAGE(bB1, B01);
    STAGE(aB0, A00); STAGE(aB1, A01);
    STAGE(bB0 + 64, B10); STAGE(bB1 + 64, B11);
    WAITV4();   // buf0 (first 8 loads) landed
    SBAR();

    for (int i = 0; i < NT2; ++i) {
        const int t1 = 2 * i + 1;                               // never wraps
        int t2 = 2 * i + 2; if (t2 >= NT) t2 -= NT;             // wraps only on last iter
        int t3 = 2 * i + 3; if (t3 >= NT) t3 -= NT;
        // P1: buf0 Q(m0-3,n0-1); stage buf1.Ah0 <- t1
        load_a4(aF, Ah0, 0, l15, k4, l7);
        load_b2<0>(bF, Bh0, brbase, l15, k4, l7);
        STAGE(aB0 + (size_t)t1 * 64, A10);
        SBAR();
        mfma16<0, 0>(acc, aF, bF);
        SBAR();
        // P2: Q(m0-3,n2-3); stage buf1.Ah1 <- t1
        load_b2<2>(bF, Bh0, brbase, l15, k4, l7);
        STAGE(aB1 + (size_t)t1 * 64, A11);
        SBAR();
        mfma16<0, 2>(acc, aF, bF);
        SBAR();
        // P3: Q(m4-7,n0-1); stage buf0.Bh0 <- t2
        load_a4(aF, Ah0, 4, l15, k4, l7);
        STAGE(bB0 + (size_t)t2 * 64, B00);
        SBAR();
        mfma16<4, 0>(acc, aF, bF);
        SBAR();
        // P4: Q(m4-7,n2-3); stage buf0.Bh1 <- t2; gate buf1
        STAGE(bB1 + (size_t)t2 * 64, B01);
        WAITV4();
        SBAR();
        mfma16<4, 2>(acc, aF, bF);
        SBAR();
        // P5: buf1 Q(m0-3,n0-1); stage buf0.Ah0 <- t2
        load_a4(aF, Ah1, 0, l15, k4, l7);
        load_b2<0>(bF, Bh1, brbase, l15, k4, l7);
        STAGE(aB0 + (size_t)t2 * 64, A00);
        SBAR();
        mfma16<0, 0>(acc, aF, bF);
        SBAR();
        // P6: Q(m0-3,n2-3); stage buf0.Ah1 <- t2
        load_b2<2>(bF, Bh1, brbase, l15, k4, l7);
        STAGE(aB1 + (size_t)t2 * 64, A01);
        SBAR();
        mfma16<0, 2>(acc, aF, bF);
        SBAR();
        // P7: Q(m4-7,n0-1); stage buf1.Bh0 <- t3
        load_a4(aF, Ah1, 4, l15, k4, l7);
        STAGE(bB0 + (size_t)t3 * 64, B10);
        SBAR();
        mfma16<4, 0>(acc, aF, bF);
        SBAR();
        // P8: Q(m4-7,n2-3); stage buf1.Bh1 <- t3; gate buf0
        STAGE(bB1 + (size_t)t3 * 64, B11);
        WAITV4();
        SBAR();
        mfma16<4, 2>(acc, aF, bF);
        SBAR();
    }
#undef STAGE

    // epilogue: C/D layout col=lane&15, row=(lane>>4)*4+reg
    ushort_t* Cb = (EPI == 1 && /*runtime*/ true)
                   ? ((bz == 2) ? (ushort_t*)Cv2 : (ushort_t*)Cv + batchC * bz)
                   : (ushort_t*)Cv + (CF32 ? 0 : batchC * bz);
    float* Cf = (float*)Cv;
    const int r0 = row0 + wr * 128 + (lane >> 4) * 4;
    const int c0 = col0 + wc * 64 + l15;
    #pragma unroll
    for (int m = 0; m < 8; ++m) {
        #pragma unroll
        for (int n = 0; n < 4; ++n) {
            const int col = c0 + n * 16;
            #pragma unroll
            for (int r = 0; r < 4; ++r) {
                const int row = r0 + m * 16 + r;
                float val = acc[m][n][r];
                if (EPI == 1) {
                    val += bf2f(bias[bz * 768 + col]);
                } else if (EPI == 2) {
                    val *= scale;
                } else if (EPI == 3) {
                    val += bf2f(bias[col]);
                    val = fmaxf(val, 0.0f);
                } else if (EPI == 4) {
                    val += bf2f(bias[col]);
                    float g  = sigm(val);
                    float gg = sigm(g);
                    val = gg * bf2f(aux[(size_t)row * N + col]) * bf2f(ts[col]);
                }
                if (CF32) Cf[(size_t)row * N + col] = val;
                else      Cb[(size_t)row * N + col] = f2bf(val);
            }
        }
    }
}

// in-place row softmax: P is [rows][S] bf16, one block (256 thr) per row, S=2048
__global__ __launch_bounds__(256)
void softmax_inplace(ushort_t* __restrict__ P, int S)
{
    const size_t row = blockIdx.x;
    ushort_t* p = P + row * (size_t)S;
    const int tid = threadIdx.x;
    const int lane = tid & 63, wave = tid >> 6;

    short8 raw = *(const short8*)(p + tid * 8);
    float x[8];
    #pragma unroll
    for (int j = 0; j < 8; ++j) x[j] = bf2f((unsigned short)raw[j]);

    float mx = x[0];
    #pragma unroll
    for (int j = 1; j < 8; ++j) mx = fmaxf(mx, x[j]);
    #pragma unroll
    for (int o = 32; o > 0; o >>= 1) mx = fmaxf(mx, __shfl_xor(mx, o));
    __shared__ float redm[4], reds[4];
    if (lane == 0) redm[wave] = mx;
    __syncthreads();
    mx = fmaxf(fmaxf(redm[0], redm[1]), fmaxf(redm[2], redm[3]));

    float s = 0.f;
    #pragma unroll
    for (int j = 0; j < 8; ++j) { x[j] = __expf(x[j] - mx); s += x[j]; }
    #pragma unroll
    for (int o = 32; o > 0; o >>= 1) s += __shfl_xor(s, o);
    if (lane == 0) reds[wave] = s;
    __syncthreads();
    s = reds[0] + reds[1] + reds[2] + reds[3];
    const float inv = 1.0f / s;

    short8 outv;
    #pragma unroll
    for (int j = 0; j < 8; ++j) outv[j] = (short)f2bf(x[j] * inv);
    *(short8*)(p + tid * 8) = outv;
}

// VT[z][c][r] = V[z][r][c];  grid (C/32, R/32, Z), block (32,8). bf16.
__global__ __launch_bounds__(256)
void transpose2d(const ushort_t* __restrict__ V, ushort_t* __restrict__ VT, int R, int Ccols)
{
    __shared__ ushort_t t[32][33];
    const size_t zoff = (size_t)blockIdx.z * R * Ccols;
    const int tx = threadIdx.x, ty = threadIdx.y;
    const int c = blockIdx.x * 32 + tx;
    const int rbase = blockIdx.y * 32;
    #pragma unroll
    for (int i = 0; i < 4; ++i)
        t[ty + i * 8][tx] = V[zoff + (size_t)(rbase + ty + i * 8) * Ccols + c];
    __syncthreads();
    const int r = rbase + tx;
    const int cbase = blockIdx.x * 32;
    #pragma unroll
    for (int i = 0; i < 4; ++i)
        VT[zoff + (size_t)(cbase + ty + i * 8) * R + r] = t[tx][ty + i * 8];
}

extern "C" void kernel_launch(void* const* d_in, const int* in_sizes, int n_in,
                              void* d_out, int out_size, void* d_ws, size_t ws_size,
                              hipStream_t stream)
{
    (void)in_sizes; (void)n_in; (void)out_size; (void)ws_size;
    const float* query = (const float*)d_in[0];
    const float* key_  = (const float*)d_in[1];
    const float* value = (const float*)d_in[2];
    const float* Wq  = (const float*)d_in[3];
    const float* bq  = (const float*)d_in[4];
    const float* Wk  = (const float*)d_in[5];
    const float* bk  = (const float*)d_in[6];
    const float* Wv  = (const float*)d_in[7];
    const float* bv  = (const float*)d_in[8];
    const float* Wg1 = (const float*)d_in[9];
    const float* bg1 = (const float*)d_in[10];
    const float* Wg2 = (const float*)d_in[11];
    const float* bg2 = (const float*)d_in[12];
    const float* tsc = (const float*)d_in[13];

    const int S = 2048, D = 768, Bc = 8;
    const int MS = Bc * S;                     // 16384
    const long long SD = (long long)S * D;     // 1,572,864
    const long long SS = (long long)S * S;     // 4,194,304
    const long long MSD = (long long)MS * D;   // 12,582,912

    // ws layout (bytes), total exactly 148,513,792 (proven available):
    //   q/att @0 (24MiB) | k/h @24MiB | vT @48MiB | P @72MiB (64MiB) | Wb @136MiB (5.9MB)
    //   X (qkv bf16 inputs, 72MiB) overlays vT+P (time-disjoint)
    char* ws = (char*)d_ws;
    ushort_t* q   = (ushort_t*)(ws);
    ushort_t* att = q;
    ushort_t* k   = (ushort_t*)(ws + 25165824ll);
    ushort_t* h   = k;
    ushort_t* vT  = (ushort_t*)(ws + 50331648ll);
    ushort_t* X   = (ushort_t*)(ws + 50331648ll);   // 3 x 24MiB, dead before vT/P written
    ushort_t* P   = (ushort_t*)(ws + 75497472ll);
    ushort_t* Wb  = (ushort_t*)(ws + 142606336ll);
    ushort_t* v   = (ushort_t*)d_out;               // bf16 v in front of d_out until transpose

    const int WQ = 0, WG1 = 1769472, WG2 = 2359296;
    const int BQ = 2949120, BG1 = 2951424, BG2 = 2952192, TSO = 2952960;

    const dim3 blk(256), blk5(512);
    const float scale = 0.03608439182435161f; // 1/sqrt(768)

    // 0. convert params + inputs to bf16
    convert_params<<<dim3((NTOT / 8 + 255) / 256), blk, 0, stream>>>(
        Wq, Wk, Wv, Wg1, Wg2, bq, bk, bv, bg1, bg2, tsc, Wb);
    convert_inputs<<<dim3(18432), blk, 0, stream>>>(query, key_, value, X);
    // 1. fused QKV projections: z=0->q, z=1->k, z=2->v(d_out)
    gemm256<1, 0><<<dim3(D / 256, MS / 256, 3), blk5, 0, stream>>>(
        X, Wb + WQ, q, v, Wb + BQ, nullptr, nullptr, MS, D, D, 1.f, MSD, (long long)WSEG, MSD);
    // 2. vT = transpose(v); X dead from here
    transpose2d<<<dim3(D / 32, S / 32, Bc), dim3(32, 8), 0, stream>>>(v, vT, S, D);
    // 3. P = q @ k^T * scale (batched)
    gemm256<2, 0><<<dim3(S / 256, S / 256, Bc), blk5, 0, stream>>>(
        q, k, P, nullptr, nullptr, nullptr, nullptr, S, S, D, scale, SD, SD, SS);
    // 4. softmax rows in-place
    softmax_inplace<<<dim3(MS), blk, 0, stream>>>(P, S);
    // 5. att = P @ vT^T (batched; att overlays q)
    gemm256<0, 0><<<dim3(D / 256, S / 256, Bc), blk5, 0, stream>>>(
        P, vT, att, nullptr, nullptr, nullptr, nullptr, S, D, S, 1.f, SS, SD, SD);
    // 6. h = relu(att @ Wg1^T + bg1)  (h overlays k)
    gemm256<3, 0><<<dim3(D / 256, MS / 256, 1), blk5, 0, stream>>>(
        att, Wb + WG1, h, nullptr, Wb + BG1, nullptr, nullptr, MS, D, D, 1.f, 0, 0, 0);
    // 7. out = sigmoid(sigmoid(h @ Wg2^T + bg2)) * att * ts  (f32 -> d_out)
    gemm256<4, 1><<<dim3(D / 256, MS / 256, 1), blk5, 0, stream>>>(
        h, Wb + WG2, d_out, nullptr, Wb + BG2, att, Wb + TSO, MS, D, D, 1.f, 0, 0, 0);
}

// Round 7
// 360.048 us; speedup vs baseline: 1.0715x; 1.0715x over previous
//
#include <hip/hip_runtime.h>

typedef unsigned short ushort_t;
typedef __bf16 bf16x8 __attribute__((ext_vector_type(8)));
typedef float f32x4 __attribute__((ext_vector_type(4)));
typedef short short8 __attribute__((ext_vector_type(8)));

#define SBAR()   asm volatile("s_barrier" ::: "memory")
#define WAITV0() asm volatile("s_waitcnt vmcnt(0)" ::: "memory")
#define WAITV2() asm volatile("s_waitcnt vmcnt(2)" ::: "memory")
#define WAITV4() asm volatile("s_waitcnt vmcnt(4)" ::: "memory")
#define WAITV6() asm volatile("s_waitcnt vmcnt(6)" ::: "memory")
#define WAITL0() asm volatile("s_waitcnt lgkmcnt(0)" ::: "memory")

__device__ __forceinline__ float bf2f(unsigned short u) {
    union { unsigned int i; float f; } v; v.i = ((unsigned int)u) << 16; return v.f;
}
__device__ __forceinline__ unsigned short f2bf(float f) {
    union { float f; unsigned int i; } v; v.f = f;
    unsigned int r = v.i + 0x7fffu + ((v.i >> 16) & 1u);
    return (unsigned short)(r >> 16);
}
__device__ __forceinline__ float sigm(float x) { return 1.0f / (1.0f + __expf(-x)); }

__device__ __forceinline__ void async_copy16(const ushort_t* src, ushort_t* dst_lds) {
    __builtin_amdgcn_global_load_lds(
        (const __attribute__((address_space(1))) void*)src,
        (__attribute__((address_space(3))) void*)dst_lds,
        16, 0, 0);
}

// ---- param conversion: 5 W (768x768) + 5 bias (768) + ts (768), f32 -> bf16 ----
#define WSEG 589824           // 768*768
#define NWALL 2949120         // 5*WSEG
#define NTOT 2953728          // + 6*768
__global__ __launch_bounds__(256)
void convert_params(const float* __restrict__ Wq, const float* __restrict__ Wk,
                    const float* __restrict__ Wv, const float* __restrict__ Wg1,
                    const float* __restrict__ Wg2, const float* __restrict__ bq,
                    const float* __restrict__ bk, const float* __restrict__ bv,
                    const float* __restrict__ bg1, const float* __restrict__ bg2,
                    const float* __restrict__ ts, ushort_t* __restrict__ dst)
{
    int i = (blockIdx.x * 256 + threadIdx.x) * 8;
    if (i >= NTOT) return;
    const float* src; int off;
    if (i < NWALL) {
        int wi = i / WSEG; off = i - wi * WSEG;
        src = (wi == 0) ? Wq : (wi == 1) ? Wk : (wi == 2) ? Wv : (wi == 3) ? Wg1 : Wg2;
    } else {
        int j = i - NWALL; int bi = j / 768; off = j - bi * 768;
        src = (bi == 0) ? bq : (bi == 1) ? bk : (bi == 2) ? bv : (bi == 3) ? bg1 : (bi == 4) ? bg2 : ts;
    }
    float4 a = *(const float4*)(src + off);
    float4 b = *(const float4*)(src + off + 4);
    short8 o;
    o[0] = (short)f2bf(a.x); o[1] = (short)f2bf(a.y); o[2] = (short)f2bf(a.z); o[3] = (short)f2bf(a.w);
    o[4] = (short)f2bf(b.x); o[5] = (short)f2bf(b.y); o[6] = (short)f2bf(b.z); o[7] = (short)f2bf(b.w);
    *(short8*)(dst + i) = o;
}

// C[M,N] = A[M,K] @ B[N,K]^T (+ epilogue), optionally batched (M = rows per batch).
// Double-buffered LDS, counted-vmcnt pipeline, raw s_barrier.
// B always bf16. AF32: A is f32 (reg-staged + cvt + ds_write). CF32: f32 store.
// QKV: gridDim.z=3; bz selects A in {Av,Av1,Av2}, dest {Cv+bz*batchC | Cv2 for bz==2}, bias+bz*768.
// EPI: 0=plain, 1=+bias, 2=*scale, 3=+bias+relu, 4=gate sigmoid(sigmoid(x+bias))*aux*ts,
//      5=exp(x*scale) [scores->P], 6=plain + in-loop row-sum of A, epilogue divide [PV softmax-norm]
// Requires gridDim.x*gridDim.y*gridDim.z % 8 == 0, K%32==0.
template<int EPI, int AF32, int CF32, int QKV>
__global__ __launch_bounds__(256, 2)
void gemm_bt(const void* __restrict__ Av, const void* __restrict__ Av1,
             const void* __restrict__ Av2, const ushort_t* __restrict__ B,
             void* __restrict__ Cv, void* __restrict__ Cv2,
             const ushort_t* __restrict__ bias,
             const ushort_t* __restrict__ aux, const ushort_t* __restrict__ ts,
             int M, int N, int K, float scale,
             long long batchA, long long batchB, long long batchC)
{
    __shared__ __align__(16) ushort_t As[2][128 * 32];
    __shared__ __align__(16) ushort_t Bs[2][128 * 32];
    __shared__ float rs[128];
    const int tid  = threadIdx.x;
    const int lane = tid & 63;
    const int wave = tid >> 6;
    const int wr = wave >> 1, wc = wave & 1;

    // XCD-aware bijective swizzle over the full flat grid (nwg % 8 == 0)
    const int gx = gridDim.x, gy = gridDim.y;
    const int nwg = gx * gy * gridDim.z;
    int fid = (blockIdx.z * gy + blockIdx.y) * gx + blockIdx.x;
    fid = (fid & 7) * (nwg >> 3) + (fid >> 3);
    const int bz  = fid / (gx * gy);
    const int rem = fid - bz * (gx * gy);
    const int by  = rem / gx;
    const int bx  = rem - by * gx;
    const int row0 = by * 128;
    const int col0 = bx * 128;

    f32x4 acc[4][4] = {};
    float psum[4] = {0.f, 0.f, 0.f, 0.f};

    // bf16 staging: 256 threads x 16B = 64 rows of 32 bf16 per inst
    const int srow = tid >> 2;
    const int scol = (tid & 3) * 8;
    const ushort_t* ga0 = (const ushort_t*)Av + batchA * bz + (size_t)(row0 + srow) * K + scol;
    const ushort_t* gb0 = B + batchB * bz + (size_t)(col0 + srow) * K + scol;
    // f32-A staging: thread t -> row t>>1, col half (t&1)*16; 16 f32 per thread
    const int arow_s = tid >> 1;
    const int acol_s = (tid & 1) * 16;
    const float* gafb = (const float*)Av;
    if (QKV) gafb = (bz == 0) ? (const float*)Av : (bz == 1) ? (const float*)Av1 : (const float*)Av2;
    const float* gaf = gafb + (QKV ? 0 : batchA * bz) + (size_t)(row0 + arow_s) * K + acol_s;

    const int kop  = (lane >> 4) * 8;
    const int arow = wr * 64 + (lane & 15);
    const int brow = wc * 64 + (lane & 15);

    const int NT = K >> 5;

    if (AF32) {
        float4 fa0 = *(const float4*)(gaf);
        float4 fa1 = *(const float4*)(gaf + 4);
        float4 fa2 = *(const float4*)(gaf + 8);
        float4 fa3 = *(const float4*)(gaf + 12);
        async_copy16(gb0,                  Bs[0] + tid * 8);
        async_copy16(gb0 + (size_t)64 * K, Bs[0] + 2048 + tid * 8);

        for (int t = 0; t < NT; ++t) {
            const int cur = t & 1;
            WAITV2();
            short8 p0, p1;
            p0[0] = (short)f2bf(fa0.x); p0[1] = (short)f2bf(fa0.y);
            p0[2] = (short)f2bf(fa0.z); p0[3] = (short)f2bf(fa0.w);
            p0[4] = (short)f2bf(fa1.x); p0[5] = (short)f2bf(fa1.y);
            p0[6] = (short)f2bf(fa1.z); p0[7] = (short)f2bf(fa1.w);
            p1[0] = (short)f2bf(fa2.x); p1[1] = (short)f2bf(fa2.y);
            p1[2] = (short)f2bf(fa2.z); p1[3] = (short)f2bf(fa2.w);
            p1[4] = (short)f2bf(fa3.x); p1[5] = (short)f2bf(fa3.y);
            p1[6] = (short)f2bf(fa3.z); p1[7] = (short)f2bf(fa3.w);
            *(short8*)(As[cur] + arow_s * 32 + acol_s)     = p0;
            *(short8*)(As[cur] + arow_s * 32 + acol_s + 8) = p1;
            if (t + 1 < NT) {
                const int k1 = (t + 1) * 32;
                fa0 = *(const float4*)(gaf + k1);
                fa1 = *(const float4*)(gaf + k1 + 4);
                fa2 = *(const float4*)(gaf + k1 + 8);
                fa3 = *(const float4*)(gaf + k1 + 12);
                async_copy16(gb0 + k1,                  Bs[cur ^ 1] + tid * 8);
                async_copy16(gb0 + (size_t)64 * K + k1, Bs[cur ^ 1] + 2048 + tid * 8);
                WAITV6();
            } else {
                WAITV0();
            }
            WAITL0();
            SBAR();
            bf16x8 af[4], bfr[4];
            #pragma unroll
            for (int m = 0; m < 4; ++m)
                af[m] = *(const bf16x8*)(As[cur] + (arow + m * 16) * 32 + kop);
            #pragma unroll
            for (int n = 0; n < 4; ++n)
                bfr[n] = *(const bf16x8*)(Bs[cur] + (brow + n * 16) * 32 + kop);
            #pragma unroll
            for (int m = 0; m < 4; ++m)
                #pragma unroll
                for (int n = 0; n < 4; ++n)
                    acc[m][n] = __builtin_amdgcn_mfma_f32_16x16x32_bf16(af[m], bfr[n], acc[m][n], 0, 0, 0);
            SBAR();
        }
    } else {
        async_copy16(ga0,                  As[0] + tid * 8);
        async_copy16(ga0 + (size_t)64 * K, As[0] + 2048 + tid * 8);
        async_copy16(gb0,                  Bs[0] + tid * 8);
        async_copy16(gb0 + (size_t)64 * K, Bs[0] + 2048 + tid * 8);

        for (int t = 0; t < NT; ++t) {
            const int cur = t & 1;
            if (t + 1 < NT) {
                const int k1 = (t + 1) * 32;
                async_copy16(ga0 + k1,                  As[cur ^ 1] + tid * 8);
                async_copy16(ga0 + (size_t)64 * K + k1, As[cur ^ 1] + 2048 + tid * 8);
                async_copy16(gb0 + k1,                  Bs[cur ^ 1] + tid * 8);
                async_copy16(gb0 + (size_t)64 * K + k1, Bs[cur ^ 1] + 2048 + tid * 8);
                WAITV4();
            } else {
                WAITV0();
            }
            SBAR();
            bf16x8 af[4], bfr[4];
            #pragma unroll
            for (int m = 0; m < 4; ++m)
                af[m] = *(const bf16x8*)(As[cur] + (arow + m * 16) * 32 + kop);
            #pragma unroll
            for (int n = 0; n < 4; ++n)
                bfr[n] = *(const bf16x8*)(Bs[cur] + (brow + n * 16) * 32 + kop);
            #pragma unroll
            for (int m = 0; m < 4; ++m)
                #pragma unroll
                for (int n = 0; n < 4; ++n)
                    acc[m][n] = __builtin_amdgcn_mfma_f32_16x16x32_bf16(af[m], bfr[n], acc[m][n], 0, 0, 0);
            if (EPI == 6) {
                // row-sum of the P fragment: af[m] holds 8 k-values of row arow+m*16;
                // xor16/xor32 reduce sums across the 4 k4-slices -> full 32-col chunk.
                #pragma unroll
                for (int m = 0; m < 4; ++m) {
                    short8 u = __builtin_bit_cast(short8, af[m]);
                    float s = bf2f((unsigned short)u[0]) + bf2f((unsigned short)u[1])
                            + bf2f((unsigned short)u[2]) + bf2f((unsigned short)u[3])
                            + bf2f((unsigned short)u[4]) + bf2f((unsigned short)u[5])
                            + bf2f((unsigned short)u[6]) + bf2f((unsigned short)u[7]);
                    s += __shfl_xor(s, 16);
                    s += __shfl_xor(s, 32);
                    psum[m] += s;
                }
            }
            SBAR();
        }
    }

    float rinv[4][4];
    if (EPI == 6) {
        if (wc == 0 && lane < 16) {
            #pragma unroll
            for (int m = 0; m < 4; ++m) rs[wr * 64 + m * 16 + lane] = psum[m];
        }
        __syncthreads();
        #pragma unroll
        for (int m = 0; m < 4; ++m)
            #pragma unroll
            for (int r = 0; r < 4; ++r)
                rinv[m][r] = 1.0f / rs[wr * 64 + m * 16 + (lane >> 4) * 4 + r];
    }

    // epilogue: C/D layout col=lane&15, row=(lane>>4)*4+reg
    ushort_t* Cb = (QKV && bz == 2) ? (ushort_t*)Cv2 : (ushort_t*)Cv + batchC * bz;
    float* Cf = (float*)Cv;
    const int r0 = row0 + wr * 64 + (lane >> 4) * 4;
    const int c0 = col0 + wc * 64 + (lane & 15);
    #pragma unroll
    for (int m = 0; m < 4; ++m) {
        #pragma unroll
        for (int n = 0; n < 4; ++n) {
            const int col = c0 + n * 16;
            #pragma unroll
            for (int r = 0; r < 4; ++r) {
                const int row = r0 + m * 16 + r;
                float val = acc[m][n][r];
                if (EPI == 1) {
                    val += bf2f(bias[(QKV ? bz * 768 : 0) + col]);
                } else if (EPI == 2) {
                    val *= scale;
                } else if (EPI == 3) {
                    val += bf2f(bias[col]);
                    val = fmaxf(val, 0.0f);
                } else if (EPI == 4) {
                    val += bf2f(bias[col]);
                    float g  = sigm(val);
                    float gg = sigm(g);
                    val = gg * bf2f(aux[(size_t)row * N + col]) * bf2f(ts[col]);
                } else if (EPI == 5) {
                    val = __expf(val * scale);
                } else if (EPI == 6) {
                    val *= rinv[m][r];
                }
                if (CF32) Cf[(size_t)row * N + col] = val;
                else      Cb[(size_t)row * N + col] = f2bf(val);
            }
        }
    }
}

// VT[z][c][r] = V[z][r][c];  grid (C/32, R/32, Z), block (32,8). bf16.
__global__ __launch_bounds__(256)
void transpose2d(const ushort_t* __restrict__ V, ushort_t* __restrict__ VT, int R, int Ccols)
{
    __shared__ ushort_t t[32][33];
    const size_t zoff = (size_t)blockIdx.z * R * Ccols;
    const int tx = threadIdx.x, ty = threadIdx.y;
    const int c = blockIdx.x * 32 + tx;
    const int rbase = blockIdx.y * 32;
    #pragma unroll
    for (int i = 0; i < 4; ++i)
        t[ty + i * 8][tx] = V[zoff + (size_t)(rbase + ty + i * 8) * Ccols + c];
    __syncthreads();
    const int r = rbase + tx;
    const int cbase = blockIdx.x * 32;
    #pragma unroll
    for (int i = 0; i < 4; ++i)
        VT[zoff + (size_t)(cbase + ty + i * 8) * R + r] = t[tx][ty + i * 8];
}

extern "C" void kernel_launch(void* const* d_in, const int* in_sizes, int n_in,
                              void* d_out, int out_size, void* d_ws, size_t ws_size,
                              hipStream_t stream)
{
    (void)in_sizes; (void)n_in; (void)out_size; (void)ws_size;
    const float* query = (const float*)d_in[0];
    const float* key_  = (const float*)d_in[1];
    const float* value = (const float*)d_in[2];
    const float* Wq  = (const float*)d_in[3];
    const float* bq  = (const float*)d_in[4];
    const float* Wk  = (const float*)d_in[5];
    const float* bk  = (const float*)d_in[6];
    const float* Wv  = (const float*)d_in[7];
    const float* bv  = (const float*)d_in[8];
    const float* Wg1 = (const float*)d_in[9];
    const float* bg1 = (const float*)d_in[10];
    const float* Wg2 = (const float*)d_in[11];
    const float* bg2 = (const float*)d_in[12];
    const float* tsc = (const float*)d_in[13];

    const int S = 2048, D = 768, Bc = 8;
    const int MS = Bc * S;                     // 16384
    const long long SD = (long long)S * D;     // 1,572,864
    const long long SS = (long long)S * S;     // 4,194,304
    const long long MSD = (long long)MS * D;   // 12,582,912

    // ws layout (bytes), total 148,513,792 (proven):
    //   q/att @0 (24MiB) | k/h @24MiB | vT @48MiB | P @72MiB (64MiB, holds exp(s)) | Wb @136MiB
    char* ws = (char*)d_ws;
    ushort_t* q   = (ushort_t*)(ws);
    ushort_t* att = q;                         // PV overwrites q after scores consumed it
    ushort_t* k   = (ushort_t*)(ws + 25165824ll);
    ushort_t* h   = k;                         // k dead after scores
    ushort_t* vT  = (ushort_t*)(ws + 50331648ll);
    ushort_t* P   = (ushort_t*)(ws + 75497472ll);
    ushort_t* Wb  = (ushort_t*)(ws + 142606336ll);
    ushort_t* v   = (ushort_t*)d_out;          // bf16 v in front of d_out until transpose

    const int WQ = 0, WG1 = 1769472, WG2 = 2359296;
    const int BQ = 2949120, BG1 = 2951424, BG2 = 2952192, TSO = 2952960;

    const dim3 blk(256);
    const float scale = 0.03608439182435161f; // 1/sqrt(768)

    // 0. convert params to bf16
    convert_params<<<dim3((NTOT / 8 + 255) / 256), blk, 0, stream>>>(
        Wq, Wk, Wv, Wg1, Wg2, bq, bk, bv, bg1, bg2, tsc, Wb);
    // 1. fused QKV projections (f32-A path): bz=0->q, 1->k, 2->v (d_out)
    gemm_bt<1, 1, 0, 1><<<dim3(D / 128, MS / 128, 3), blk, 0, stream>>>(
        query, key_, value, Wb + WQ, q, v, Wb + BQ, nullptr, nullptr,
        MS, D, D, 1.f, 0, (long long)WSEG, MSD);
    // 2. vT = transpose(v) per batch; v dead afterwards
    transpose2d<<<dim3(D / 32, S / 32, Bc), dim3(32, 8), 0, stream>>>(v, vT, S, D);
    // 3. P = exp(q @ k^T * scale)  (batched; no max-subtraction needed, |s|<~5)
    gemm_bt<5, 0, 0, 0><<<dim3(S / 128, S / 128, Bc), blk, 0, stream>>>(
        q, nullptr, nullptr, k, P, nullptr, nullptr, nullptr, nullptr,
        S, S, D, scale, SD, SD, SS);
    // 4. att = (P @ vT^T) / rowsum(P)   (batched; rowsum computed in-loop; att overlays q)
    gemm_bt<6, 0, 0, 0><<<dim3(D / 128, S / 128, Bc), blk, 0, stream>>>(
        P, nullptr, nullptr, vT, att, nullptr, nullptr, nullptr, nullptr,
        S, D, S, 1.f, SS, SD, SD);
    // 5. h = relu(att @ Wg1^T + bg1)  (h overlays k)
    gemm_bt<3, 0, 0, 0><<<dim3(D / 128, MS / 128, 1), blk, 0, stream>>>(
        att, nullptr, nullptr, Wb + WG1, h, nullptr, Wb + BG1, nullptr, nullptr,
        MS, D, D, 1.f, 0, 0, 0);
    // 6. out = sigmoid(sigmoid(h @ Wg2^T + bg2)) * att * ts  (f32 -> d_out)
    gemm_bt<4, 0, 1, 0><<<dim3(D / 128, MS / 128, 1), blk, 0, stream>>>(
        h, nullptr, nullptr, Wb + WG2, d_out, nullptr, Wb + BG2, att, Wb + TSO,
        MS, D, D, 1.f, 0, 0, 0);
}

// Round 8
// 349.125 us; speedup vs baseline: 1.1050x; 1.0313x over previous
//
#include <hip/hip_runtime.h>

typedef unsigned short ushort_t;
typedef __bf16 bf16x8 __attribute__((ext_vector_type(8)));
typedef float f32x4 __attribute__((ext_vector_type(4)));
typedef short short8 __attribute__((ext_vector_type(8)));

#define SBAR()   asm volatile("s_barrier" ::: "memory")
#define WAITV0() asm volatile("s_waitcnt vmcnt(0)" ::: "memory")
#define WAITV4() asm volatile("s_waitcnt vmcnt(4)" ::: "memory")

__device__ __forceinline__ float bf2f(unsigned short u) {
    union { unsigned int i; float f; } v; v.i = ((unsigned int)u) << 16; return v.f;
}
__device__ __forceinline__ unsigned short f2bf(float f) {
    union { float f; unsigned int i; } v; v.f = f;
    unsigned int r = v.i + 0x7fffu + ((v.i >> 16) & 1u);
    return (unsigned short)(r >> 16);
}
__device__ __forceinline__ float sigm(float x) { return 1.0f / (1.0f + __expf(-x)); }

__device__ __forceinline__ void async_copy16(const ushort_t* src, ushort_t* dst_lds) {
    __builtin_amdgcn_global_load_lds(
        (const __attribute__((address_space(1))) void*)src,
        (__attribute__((address_space(3))) void*)dst_lds,
        16, 0, 0);
}

// ---- param conversion: 5 W (768x768) + 5 bias (768) + ts (768), f32 -> bf16 ----
#define WSEG 589824           // 768*768
#define NWALL 2949120         // 5*WSEG
#define NTOT 2953728          // + 6*768
__global__ __launch_bounds__(256)
void convert_params(const float* __restrict__ Wq, const float* __restrict__ Wk,
                    const float* __restrict__ Wv, const float* __restrict__ Wg1,
                    const float* __restrict__ Wg2, const float* __restrict__ bq,
                    const float* __restrict__ bk, const float* __restrict__ bv,
                    const float* __restrict__ bg1, const float* __restrict__ bg2,
                    const float* __restrict__ ts, ushort_t* __restrict__ dst)
{
    int i = (blockIdx.x * 256 + threadIdx.x) * 8;
    if (i >= NTOT) return;
    const float* src; int off;
    if (i < NWALL) {
        int wi = i / WSEG; off = i - wi * WSEG;
        src = (wi == 0) ? Wq : (wi == 1) ? Wk : (wi == 2) ? Wv : (wi == 3) ? Wg1 : Wg2;
    } else {
        int j = i - NWALL; int bi = j / 768; off = j - bi * 768;
        src = (bi == 0) ? bq : (bi == 1) ? bk : (bi == 2) ? bv : (bi == 3) ? bg1 : (bi == 4) ? bg2 : ts;
    }
    float4 a = *(const float4*)(src + off);
    float4 b = *(const float4*)(src + off + 4);
    short8 o;
    o[0] = (short)f2bf(a.x); o[1] = (short)f2bf(a.y); o[2] = (short)f2bf(a.z); o[3] = (short)f2bf(a.w);
    o[4] = (short)f2bf(b.x); o[5] = (short)f2bf(b.y); o[6] = (short)f2bf(b.z); o[7] = (short)f2bf(b.w);
    *(short8*)(dst + i) = o;
}

// ---- input conversion: query/key/value [16384x768] f32 -> bf16 into X[3] ----
#define PERT 12582912ll
__global__ __launch_bounds__(256)
void convert_inputs(const float* __restrict__ q, const float* __restrict__ k,
                    const float* __restrict__ v, ushort_t* __restrict__ X)
{
    long long i = ((long long)blockIdx.x * 256 + threadIdx.x) * 8;
    const float* src; long long off;
    if (i < PERT)          { src = q; off = i; }
    else if (i < 2 * PERT) { src = k; off = i - PERT; }
    else                   { src = v; off = i - 2 * PERT; }
    float4 a = *(const float4*)(src + off);
    float4 b = *(const float4*)(src + off + 4);
    short8 o;
    o[0] = (short)f2bf(a.x); o[1] = (short)f2bf(a.y); o[2] = (short)f2bf(a.z); o[3] = (short)f2bf(a.w);
    o[4] = (short)f2bf(b.x); o[5] = (short)f2bf(b.y); o[6] = (short)f2bf(b.z); o[7] = (short)f2bf(b.w);
    *(short8*)(X + i) = o;
}

// C[M,N] = A[M,K] @ B[N,K]^T (+ epilogue), optionally batched (M = rows per batch).
// All-bf16 operands via global_load_lds; double-buffered LDS, counted-vmcnt, raw s_barrier.
// CF32: f32 store. QKV: gridDim.z=3; bz selects dest {Cv+bz*batchC | Cv2 for bz==2}, bias+bz*768.
// EPI: 0=plain, 1=+bias, 3=+bias+relu, 4=gate sigmoid(sigmoid(x+bias))*aux*ts,
//      5=exp(x*scale) [scores->P], 6=plain + in-loop row-sum of A, epilogue divide [PV softmax-norm]
// Requires gridDim.x*gridDim.y*gridDim.z % 8 == 0, K%32==0.
template<int EPI, int CF32, int QKV>
__global__ __launch_bounds__(256, 2)
void gemm_bt(const ushort_t* __restrict__ A, const ushort_t* __restrict__ B,
             void* __restrict__ Cv, void* __restrict__ Cv2,
             const ushort_t* __restrict__ bias,
             const ushort_t* __restrict__ aux, const ushort_t* __restrict__ ts,
             int M, int N, int K, float scale,
             long long batchA, long long batchB, long long batchC)
{
    __shared__ __align__(16) ushort_t As[2][128 * 32];
    __shared__ __align__(16) ushort_t Bs[2][128 * 32];
    __shared__ float rs[128];
    const int tid  = threadIdx.x;
    const int lane = tid & 63;
    const int wave = tid >> 6;
    const int wr = wave >> 1, wc = wave & 1;

    // XCD-aware bijective swizzle over the full flat grid (nwg % 8 == 0)
    const int gx = gridDim.x, gy = gridDim.y;
    const int nwg = gx * gy * gridDim.z;
    int fid = (blockIdx.z * gy + blockIdx.y) * gx + blockIdx.x;
    fid = (fid & 7) * (nwg >> 3) + (fid >> 3);
    const int bz  = fid / (gx * gy);
    const int rem = fid - bz * (gx * gy);
    const int by  = rem / gx;
    const int bx  = rem - by * gx;
    const int row0 = by * 128;
    const int col0 = bx * 128;

    f32x4 acc[4][4] = {};
    float psum[4] = {0.f, 0.f, 0.f, 0.f};

    // staging: 256 threads x 16B = 64 rows of 32 bf16 per inst
    const int srow = tid >> 2;
    const int scol = (tid & 3) * 8;
    const ushort_t* ga0 = A + batchA * bz + (size_t)(row0 + srow) * K + scol;
    const ushort_t* gb0 = B + batchB * bz + (size_t)(col0 + srow) * K + scol;

    const int kop  = (lane >> 4) * 8;
    const int arow = wr * 64 + (lane & 15);
    const int brow = wc * 64 + (lane & 15);

    const int NT = K >> 5;

    async_copy16(ga0,                  As[0] + tid * 8);
    async_copy16(ga0 + (size_t)64 * K, As[0] + 2048 + tid * 8);
    async_copy16(gb0,                  Bs[0] + tid * 8);
    async_copy16(gb0 + (size_t)64 * K, Bs[0] + 2048 + tid * 8);

    for (int t = 0; t < NT; ++t) {
        const int cur = t & 1;
        if (t + 1 < NT) {
            const int k1 = (t + 1) * 32;
            async_copy16(ga0 + k1,                  As[cur ^ 1] + tid * 8);
            async_copy16(ga0 + (size_t)64 * K + k1, As[cur ^ 1] + 2048 + tid * 8);
            async_copy16(gb0 + k1,                  Bs[cur ^ 1] + tid * 8);
            async_copy16(gb0 + (size_t)64 * K + k1, Bs[cur ^ 1] + 2048 + tid * 8);
            WAITV4();   // tile t landed; tile t+1 (4 loads) in flight
        } else {
            WAITV0();
        }
        SBAR();
        bf16x8 af[4], bfr[4];
        #pragma unroll
        for (int m = 0; m < 4; ++m)
            af[m] = *(const bf16x8*)(As[cur] + (arow + m * 16) * 32 + kop);
        #pragma unroll
        for (int n = 0; n < 4; ++n)
            bfr[n] = *(const bf16x8*)(Bs[cur] + (brow + n * 16) * 32 + kop);
        #pragma unroll
        for (int m = 0; m < 4; ++m)
            #pragma unroll
            for (int n = 0; n < 4; ++n)
                acc[m][n] = __builtin_amdgcn_mfma_f32_16x16x32_bf16(af[m], bfr[n], acc[m][n], 0, 0, 0);
        if (EPI == 6) {
            // row-sum of P fragment: af[m] holds 8 k-values of row arow+m*16;
            // xor16/xor32 sum across the 4 k4-slices -> full 32-col chunk.
            #pragma unroll
            for (int m = 0; m < 4; ++m) {
                short8 u = __builtin_bit_cast(short8, af[m]);
                float s = bf2f((unsigned short)u[0]) + bf2f((unsigned short)u[1])
                        + bf2f((unsigned short)u[2]) + bf2f((unsigned short)u[3])
                        + bf2f((unsigned short)u[4]) + bf2f((unsigned short)u[5])
                        + bf2f((unsigned short)u[6]) + bf2f((unsigned short)u[7]);
                s += __shfl_xor(s, 16);
                s += __shfl_xor(s, 32);
                psum[m] += s;
            }
        }
        SBAR();
    }

    float rinv[4][4];
    if (EPI == 6) {
        if (wc == 0 && lane < 16) {
            #pragma unroll
            for (int m = 0; m < 4; ++m) rs[wr * 64 + m * 16 + lane] = psum[m];
        }
        __syncthreads();
        #pragma unroll
        for (int m = 0; m < 4; ++m)
            #pragma unroll
            for (int r = 0; r < 4; ++r)
                rinv[m][r] = 1.0f / rs[wr * 64 + m * 16 + (lane >> 4) * 4 + r];
    }

    // epilogue: C/D layout col=lane&15, row=(lane>>4)*4+reg
    ushort_t* Cb = (QKV && bz == 2) ? (ushort_t*)Cv2 : (ushort_t*)Cv + batchC * bz;
    float* Cf = (float*)Cv;
    const int r0 = row0 + wr * 64 + (lane >> 4) * 4;
    const int c0 = col0 + wc * 64 + (lane & 15);
    #pragma unroll
    for (int m = 0; m < 4; ++m) {
        #pragma unroll
        for (int n = 0; n < 4; ++n) {
            const int col = c0 + n * 16;
            #pragma unroll
            for (int r = 0; r < 4; ++r) {
                const int row = r0 + m * 16 + r;
                float val = acc[m][n][r];
                if (EPI == 1) {
                    val += bf2f(bias[(QKV ? bz * 768 : 0) + col]);
                } else if (EPI == 3) {
                    val += bf2f(bias[col]);
                    val = fmaxf(val, 0.0f);
                } else if (EPI == 4) {
                    val += bf2f(bias[col]);
                    float g  = sigm(val);
                    float gg = sigm(g);
                    val = gg * bf2f(aux[(size_t)row * N + col]) * bf2f(ts[col]);
                } else if (EPI == 5) {
                    val = __expf(val * scale);
                } else if (EPI == 6) {
                    val *= rinv[m][r];
                }
                if (CF32) Cf[(size_t)row * N + col] = val;
                else      Cb[(size_t)row * N + col] = f2bf(val);
            }
        }
    }
}

// VT[z][c][r] = V[z][r][c];  grid (C/32, R/32, Z), block (32,8). bf16.
__global__ __launch_bounds__(256)
void transpose2d(const ushort_t* __restrict__ V, ushort_t* __restrict__ VT, int R, int Ccols)
{
    __shared__ ushort_t t[32][33];
    const size_t zoff = (size_t)blockIdx.z * R * Ccols;
    const int tx = threadIdx.x, ty = threadIdx.y;
    const int c = blockIdx.x * 32 + tx;
    const int rbase = blockIdx.y * 32;
    #pragma unroll
    for (int i = 0; i < 4; ++i)
        t[ty + i * 8][tx] = V[zoff + (size_t)(rbase + ty + i * 8) * Ccols + c];
    __syncthreads();
    const int r = rbase + tx;
    const int cbase = blockIdx.x * 32;
    #pragma unroll
    for (int i = 0; i < 4; ++i)
        VT[zoff + (size_t)(cbase + ty + i * 8) * R + r] = t[tx][ty + i * 8];
}

extern "C" void kernel_launch(void* const* d_in, const int* in_sizes, int n_in,
                              void* d_out, int out_size, void* d_ws, size_t ws_size,
                              hipStream_t stream)
{
    (void)in_sizes; (void)n_in; (void)out_size; (void)ws_size;
    const float* query = (const float*)d_in[0];
    const float* key_  = (const float*)d_in[1];
    const float* value = (const float*)d_in[2];
    const float* Wq  = (const float*)d_in[3];
    const float* bq  = (const float*)d_in[4];
    const float* Wk  = (const float*)d_in[5];
    const float* bk  = (const float*)d_in[6];
    const float* Wv  = (const float*)d_in[7];
    const float* bv  = (const float*)d_in[8];
    const float* Wg1 = (const float*)d_in[9];
    const float* bg1 = (const float*)d_in[10];
    const float* Wg2 = (const float*)d_in[11];
    const float* bg2 = (const float*)d_in[12];
    const float* tsc = (const float*)d_in[13];

    const int S = 2048, D = 768, Bc = 8;
    const int MS = Bc * S;                     // 16384
    const long long SD = (long long)S * D;     // 1,572,864
    const long long SS = (long long)S * S;     // 4,194,304
    const long long MSD = (long long)MS * D;   // 12,582,912

    // ws layout (bytes), total 148,513,792 (proven):
    //   q/att @0 (24MiB) | k/h @24MiB | vT @48MiB | P @72MiB (64MiB) | Wb @136MiB
    //   X (qkv bf16 inputs, 72MiB) @48MiB overlays vT+P (time-disjoint: X dead before vT/P written)
    char* ws = (char*)d_ws;
    ushort_t* q   = (ushort_t*)(ws);
    ushort_t* att = q;                         // PV overwrites q after scores consumed it
    ushort_t* k   = (ushort_t*)(ws + 25165824ll);
    ushort_t* h   = k;                         // k dead after scores
    ushort_t* vT  = (ushort_t*)(ws + 50331648ll);
    ushort_t* X   = (ushort_t*)(ws + 50331648ll);   // 3 x 24MiB
    ushort_t* P   = (ushort_t*)(ws + 75497472ll);
    ushort_t* Wb  = (ushort_t*)(ws + 142606336ll);
    ushort_t* v   = (ushort_t*)d_out;          // bf16 v in front of d_out until transpose

    const int WQ = 0, WG1 = 1769472, WG2 = 2359296;
    const int BQ = 2949120, BG1 = 2951424, BG2 = 2952192, TSO = 2952960;

    const dim3 blk(256);
    const float scale = 0.03608439182435161f; // 1/sqrt(768)

    // 0. convert params + inputs to bf16 (numerically identical rounding to in-loop cvt)
    convert_params<<<dim3((NTOT / 8 + 255) / 256), blk, 0, stream>>>(
        Wq, Wk, Wv, Wg1, Wg2, bq, bk, bv, bg1, bg2, tsc, Wb);
    convert_inputs<<<dim3(18432), blk, 0, stream>>>(query, key_, value, X);
    // 1. fused QKV projections (all-bf16 path): bz=0->q, 1->k, 2->v (d_out)
    gemm_bt<1, 0, 1><<<dim3(D / 128, MS / 128, 3), blk, 0, stream>>>(
        X, Wb + WQ, q, v, Wb + BQ, nullptr, nullptr,
        MS, D, D, 1.f, MSD, (long long)WSEG, MSD);
    // 2. vT = transpose(v) per batch; v and X dead afterwards
    transpose2d<<<dim3(D / 32, S / 32, Bc), dim3(32, 8), 0, stream>>>(v, vT, S, D);
    // 3. P = exp(q @ k^T * scale)  (batched; no max-subtraction needed, |s| < ~5)
    gemm_bt<5, 0, 0><<<dim3(S / 128, S / 128, Bc), blk, 0, stream>>>(
        q, k, P, nullptr, nullptr, nullptr, nullptr,
        S, S, D, scale, SD, SD, SS);
    // 4. att = (P @ vT^T) / rowsum(P)   (batched; rowsum in-loop; att overlays q)
    gemm_bt<6, 0, 0><<<dim3(D / 128, S / 128, Bc), blk, 0, stream>>>(
        P, vT, att, nullptr, nullptr, nullptr, nullptr,
        S, D, S, 1.f, SS, SD, SD);
    // 5. h = relu(att @ Wg1^T + bg1)  (h overlays k)
    gemm_bt<3, 0, 0><<<dim3(D / 128, MS / 128, 1), blk, 0, stream>>>(
        att, Wb + WG1, h, nullptr, Wb + BG1, nullptr, nullptr,
        MS, D, D, 1.f, 0, 0, 0);
    // 6. out = sigmoid(sigmoid(h @ Wg2^T + bg2)) * att * ts  (f32 -> d_out)
    gemm_bt<4, 1, 0><<<dim3(D / 128, MS / 128, 1), blk, 0, stream>>>(
        h, Wb + WG2, d_out, nullptr, Wb + BG2, att, Wb + TSO,
        MS, D, D, 1.f, 0, 0, 0);
}

// Round 9
// 337.260 us; speedup vs baseline: 1.1439x; 1.0352x over previous
//
#include <hip/hip_runtime.h>

typedef unsigned short ushort_t;
typedef __bf16 bf16x8 __attribute__((ext_vector_type(8)));
typedef float f32x4 __attribute__((ext_vector_type(4)));
typedef short short8 __attribute__((ext_vector_type(8)));

#define SBAR()   asm volatile("s_barrier" ::: "memory")
#define WAITV0() asm volatile("s_waitcnt vmcnt(0)" ::: "memory")
#define WAITV4() asm volatile("s_waitcnt vmcnt(4)" ::: "memory")

__device__ __forceinline__ float bf2f(unsigned short u) {
    union { unsigned int i; float f; } v; v.i = ((unsigned int)u) << 16; return v.f;
}
__device__ __forceinline__ unsigned short f2bf(float f) {
    union { float f; unsigned int i; } v; v.f = f;
    unsigned int r = v.i + 0x7fffu + ((v.i >> 16) & 1u);
    return (unsigned short)(r >> 16);
}
__device__ __forceinline__ float sigm(float x) { return 1.0f / (1.0f + __expf(-x)); }

__device__ __forceinline__ void async_copy16(const ushort_t* src, ushort_t* dst_lds) {
    __builtin_amdgcn_global_load_lds(
        (const __attribute__((address_space(1))) void*)src,
        (__attribute__((address_space(3))) void*)dst_lds,
        16, 0, 0);
}

// ---- param conversion: 5 W (768x768) + 5 bias (768) + ts (768), f32 -> bf16 ----
#define WSEG 589824           // 768*768
#define NWALL 2949120         // 5*WSEG
#define NTOT 2953728          // + 6*768
__global__ __launch_bounds__(256)
void convert_params(const float* __restrict__ Wq, const float* __restrict__ Wk,
                    const float* __restrict__ Wv, const float* __restrict__ Wg1,
                    const float* __restrict__ Wg2, const float* __restrict__ bq,
                    const float* __restrict__ bk, const float* __restrict__ bv,
                    const float* __restrict__ bg1, const float* __restrict__ bg2,
                    const float* __restrict__ ts, ushort_t* __restrict__ dst)
{
    int i = (blockIdx.x * 256 + threadIdx.x) * 8;
    if (i >= NTOT) return;
    const float* src; int off;
    if (i < NWALL) {
        int wi = i / WSEG; off = i - wi * WSEG;
        src = (wi == 0) ? Wq : (wi == 1) ? Wk : (wi == 2) ? Wv : (wi == 3) ? Wg1 : Wg2;
    } else {
        int j = i - NWALL; int bi = j / 768; off = j - bi * 768;
        src = (bi == 0) ? bq : (bi == 1) ? bk : (bi == 2) ? bv : (bi == 3) ? bg1 : (bi == 4) ? bg2 : ts;
    }
    float4 a = *(const float4*)(src + off);
    float4 b = *(const float4*)(src + off + 4);
    short8 o;
    o[0] = (short)f2bf(a.x); o[1] = (short)f2bf(a.y); o[2] = (short)f2bf(a.z); o[3] = (short)f2bf(a.w);
    o[4] = (short)f2bf(b.x); o[5] = (short)f2bf(b.y); o[6] = (short)f2bf(b.z); o[7] = (short)f2bf(b.w);
    *(short8*)(dst + i) = o;
}

// ---- input conversion: query/key/value [16384x768] f32 -> bf16 into X[3] ----
#define PERT 12582912ll
__global__ __launch_bounds__(256)
void convert_inputs(const float* __restrict__ q, const float* __restrict__ k,
                    const float* __restrict__ v, ushort_t* __restrict__ X)
{
    long long i = ((long long)blockIdx.x * 256 + threadIdx.x) * 8;
    const float* src; long long off;
    if (i < PERT)          { src = q; off = i; }
    else if (i < 2 * PERT) { src = k; off = i - PERT; }
    else                   { src = v; off = i - 2 * PERT; }
    float4 a = *(const float4*)(src + off);
    float4 b = *(const float4*)(src + off + 4);
    short8 o;
    o[0] = (short)f2bf(a.x); o[1] = (short)f2bf(a.y); o[2] = (short)f2bf(a.z); o[3] = (short)f2bf(a.w);
    o[4] = (short)f2bf(b.x); o[5] = (short)f2bf(b.y); o[6] = (short)f2bf(b.z); o[7] = (short)f2bf(b.w);
    *(short8*)(X + i) = o;
}

// ---- row-sum inverse: rinv[row] = 1 / sum(P[row][0..S-1]); one block per row ----
__global__ __launch_bounds__(256)
void rowsum_inv(const ushort_t* __restrict__ P, float* __restrict__ rinv, int S)
{
    const size_t row = blockIdx.x;
    const ushort_t* p = P + row * (size_t)S;
    const int tid = threadIdx.x;
    const int lane = tid & 63, wave = tid >> 6;

    short8 raw = *(const short8*)(p + tid * 8);
    float s = 0.f;
    #pragma unroll
    for (int j = 0; j < 8; ++j) s += bf2f((unsigned short)raw[j]);
    #pragma unroll
    for (int o = 32; o > 0; o >>= 1) s += __shfl_xor(s, o);
    __shared__ float red[4];
    if (lane == 0) red[wave] = s;
    __syncthreads();
    if (tid == 0) rinv[row] = 1.0f / (red[0] + red[1] + red[2] + red[3]);
}

// C[M,N] = A[M,K] @ B[N,K]^T (+ epilogue), optionally batched (M = rows per batch).
// All-bf16 operands via global_load_lds; double-buffered LDS, counted-vmcnt, raw s_barrier.
// CF32: f32 store. QKV: gridDim.z=3; bz selects dest {Cv+bz*batchC | Cv2 for bz==2}, bias+bz*768.
// EPI: 0=plain, 1=+bias, 3=+bias+relu, 4=gate sigmoid(sigmoid(x+bias))*aux*ts,
//      5=exp(x*scale) [scores->P], 7=multiply by rinvg[bz*M+row] [PV softmax-norm]
// Requires gridDim.x*gridDim.y*gridDim.z % 8 == 0, K%32==0.
template<int EPI, int CF32, int QKV>
__global__ __launch_bounds__(256, 2)
void gemm_bt(const ushort_t* __restrict__ A, const ushort_t* __restrict__ B,
             void* __restrict__ Cv, void* __restrict__ Cv2,
             const ushort_t* __restrict__ bias,
             const ushort_t* __restrict__ aux, const ushort_t* __restrict__ ts,
             const float* __restrict__ rinvg,
             int M, int N, int K, float scale,
             long long batchA, long long batchB, long long batchC)
{
    __shared__ __align__(16) ushort_t As[2][128 * 32];
    __shared__ __align__(16) ushort_t Bs[2][128 * 32];
    const int tid  = threadIdx.x;
    const int lane = tid & 63;
    const int wave = tid >> 6;
    const int wr = wave >> 1, wc = wave & 1;

    // XCD-aware bijective swizzle over the full flat grid (nwg % 8 == 0)
    const int gx = gridDim.x, gy = gridDim.y;
    const int nwg = gx * gy * gridDim.z;
    int fid = (blockIdx.z * gy + blockIdx.y) * gx + blockIdx.x;
    fid = (fid & 7) * (nwg >> 3) + (fid >> 3);
    const int bz  = fid / (gx * gy);
    const int rem = fid - bz * (gx * gy);
    const int by  = rem / gx;
    const int bx  = rem - by * gx;
    const int row0 = by * 128;
    const int col0 = bx * 128;

    f32x4 acc[4][4] = {};

    // staging: 256 threads x 16B = 64 rows of 32 bf16 per inst
    const int srow = tid >> 2;
    const int scol = (tid & 3) * 8;
    const ushort_t* ga0 = A + batchA * bz + (size_t)(row0 + srow) * K + scol;
    const ushort_t* gb0 = B + batchB * bz + (size_t)(col0 + srow) * K + scol;

    const int kop  = (lane >> 4) * 8;
    const int arow = wr * 64 + (lane & 15);
    const int brow = wc * 64 + (lane & 15);

    const int NT = K >> 5;

    async_copy16(ga0,                  As[0] + tid * 8);
    async_copy16(ga0 + (size_t)64 * K, As[0] + 2048 + tid * 8);
    async_copy16(gb0,                  Bs[0] + tid * 8);
    async_copy16(gb0 + (size_t)64 * K, Bs[0] + 2048 + tid * 8);

    for (int t = 0; t < NT; ++t) {
        const int cur = t & 1;
        if (t + 1 < NT) {
            const int k1 = (t + 1) * 32;
            async_copy16(ga0 + k1,                  As[cur ^ 1] + tid * 8);
            async_copy16(ga0 + (size_t)64 * K + k1, As[cur ^ 1] + 2048 + tid * 8);
            async_copy16(gb0 + k1,                  Bs[cur ^ 1] + tid * 8);
            async_copy16(gb0 + (size_t)64 * K + k1, Bs[cur ^ 1] + 2048 + tid * 8);
            WAITV4();   // tile t landed; tile t+1 (4 loads) in flight
        } else {
            WAITV0();
        }
        SBAR();
        bf16x8 af[4], bfr[4];
        #pragma unroll
        for (int m = 0; m < 4; ++m)
            af[m] = *(const bf16x8*)(As[cur] + (arow + m * 16) * 32 + kop);
        #pragma unroll
        for (int n = 0; n < 4; ++n)
            bfr[n] = *(const bf16x8*)(Bs[cur] + (brow + n * 16) * 32 + kop);
        #pragma unroll
        for (int m = 0; m < 4; ++m)
            #pragma unroll
            for (int n = 0; n < 4; ++n)
                acc[m][n] = __builtin_amdgcn_mfma_f32_16x16x32_bf16(af[m], bfr[n], acc[m][n], 0, 0, 0);
        SBAR();
    }

    // epilogue: C/D layout col=lane&15, row=(lane>>4)*4+reg
    const int r0 = row0 + wr * 64 + (lane >> 4) * 4;
    const int c0 = col0 + wc * 64 + (lane & 15);

    float rv[4][4];
    if (EPI == 7) {
        #pragma unroll
        for (int m = 0; m < 4; ++m)
            #pragma unroll
            for (int r = 0; r < 4; ++r)
                rv[m][r] = rinvg[(size_t)bz * M + r0 + m * 16 + r];
    }

    ushort_t* Cb = (QKV && bz == 2) ? (ushort_t*)Cv2 : (ushort_t*)Cv + batchC * bz;
    float* Cf = (float*)Cv;
    #pragma unroll
    for (int m = 0; m < 4; ++m) {
        #pragma unroll
        for (int n = 0; n < 4; ++n) {
            const int col = c0 + n * 16;
            #pragma unroll
            for (int r = 0; r < 4; ++r) {
                const int row = r0 + m * 16 + r;
                float val = acc[m][n][r];
                if (EPI == 1) {
                    val += bf2f(bias[(QKV ? bz * 768 : 0) + col]);
                } else if (EPI == 3) {
                    val += bf2f(bias[col]);
                    val = fmaxf(val, 0.0f);
                } else if (EPI == 4) {
                    val += bf2f(bias[col]);
                    float g  = sigm(val);
                    float gg = sigm(g);
                    val = gg * bf2f(aux[(size_t)row * N + col]) * bf2f(ts[col]);
                } else if (EPI == 5) {
                    val = __expf(val * scale);
                } else if (EPI == 7) {
                    val *= rv[m][r];
                }
                if (CF32) Cf[(size_t)row * N + col] = val;
                else      Cb[(size_t)row * N + col] = f2bf(val);
            }
        }
    }
}

// VT[z][c][r] = V[z][r][c];  grid (C/32, R/32, Z), block (32,8). bf16.
__global__ __launch_bounds__(256)
void transpose2d(const ushort_t* __restrict__ V, ushort_t* __restrict__ VT, int R, int Ccols)
{
    __shared__ ushort_t t[32][33];
    const size_t zoff = (size_t)blockIdx.z * R * Ccols;
    const int tx = threadIdx.x, ty = threadIdx.y;
    const int c = blockIdx.x * 32 + tx;
    const int rbase = blockIdx.y * 32;
    #pragma unroll
    for (int i = 0; i < 4; ++i)
        t[ty + i * 8][tx] = V[zoff + (size_t)(rbase + ty + i * 8) * Ccols + c];
    __syncthreads();
    const int r = rbase + tx;
    const int cbase = blockIdx.x * 32;
    #pragma unroll
    for (int i = 0; i < 4; ++i)
        VT[zoff + (size_t)(cbase + ty + i * 8) * R + r] = t[tx][ty + i * 8];
}

extern "C" void kernel_launch(void* const* d_in, const int* in_sizes, int n_in,
                              void* d_out, int out_size, void* d_ws, size_t ws_size,
                              hipStream_t stream)
{
    (void)in_sizes; (void)n_in; (void)out_size; (void)ws_size;
    const float* query = (const float*)d_in[0];
    const float* key_  = (const float*)d_in[1];
    const float* value = (const float*)d_in[2];
    const float* Wq  = (const float*)d_in[3];
    const float* bq  = (const float*)d_in[4];
    const float* Wk  = (const float*)d_in[5];
    const float* bk  = (const float*)d_in[6];
    const float* Wv  = (const float*)d_in[7];
    const float* bv  = (const float*)d_in[8];
    const float* Wg1 = (const float*)d_in[9];
    const float* bg1 = (const float*)d_in[10];
    const float* Wg2 = (const float*)d_in[11];
    const float* bg2 = (const float*)d_in[12];
    const float* tsc = (const float*)d_in[13];

    const int S = 2048, D = 768, Bc = 8;
    const int MS = Bc * S;                     // 16384
    const long long SD = (long long)S * D;     // 1,572,864
    const long long SS = (long long)S * S;     // 4,194,304
    const long long MSD = (long long)MS * D;   // 12,582,912

    // ws layout (bytes), total 148,513,792 (proven):
    //   q/att @0 (24MiB) | k/rinv/h @24MiB | vT @48MiB | P @72MiB (64MiB) | Wb @136MiB
    //   X (qkv bf16, 72MiB) @48MiB overlays vT+P (dead before vT/P written)
    //   rinv (64KB) overlays k (k dead after scores; h written only after PV consumed rinv)
    char* ws = (char*)d_ws;
    ushort_t* q    = (ushort_t*)(ws);
    ushort_t* att  = q;                        // PV overwrites q after scores consumed it
    ushort_t* k    = (ushort_t*)(ws + 25165824ll);
    float*    rinv = (float*)(ws + 25165824ll);
    ushort_t* h    = k;
    ushort_t* vT   = (ushort_t*)(ws + 50331648ll);
    ushort_t* X    = (ushort_t*)(ws + 50331648ll);  // 3 x 24MiB
    ushort_t* P    = (ushort_t*)(ws + 75497472ll);
    ushort_t* Wb   = (ushort_t*)(ws + 142606336ll);
    ushort_t* v    = (ushort_t*)d_out;         // bf16 v in front of d_out until transpose

    const int WQ = 0, WG1 = 1769472, WG2 = 2359296;
    const int BQ = 2949120, BG1 = 2951424, BG2 = 2952192, TSO = 2952960;

    const dim3 blk(256);
    const float scale = 0.03608439182435161f; // 1/sqrt(768)

    // 0. convert params + inputs to bf16
    convert_params<<<dim3((NTOT / 8 + 255) / 256), blk, 0, stream>>>(
        Wq, Wk, Wv, Wg1, Wg2, bq, bk, bv, bg1, bg2, tsc, Wb);
    convert_inputs<<<dim3(18432), blk, 0, stream>>>(query, key_, value, X);
    // 1. fused QKV projections: bz=0->q, 1->k, 2->v (d_out)
    gemm_bt<1, 0, 1><<<dim3(D / 128, MS / 128, 3), blk, 0, stream>>>(
        X, Wb + WQ, q, v, Wb + BQ, nullptr, nullptr, nullptr,
        MS, D, D, 1.f, MSD, (long long)WSEG, MSD);
    // 2. vT = transpose(v) per batch; v and X dead afterwards
    transpose2d<<<dim3(D / 32, S / 32, Bc), dim3(32, 8), 0, stream>>>(v, vT, S, D);
    // 3. P = exp(q @ k^T * scale)  (batched; no max-subtraction needed, |s| < ~5)
    gemm_bt<5, 0, 0><<<dim3(S / 128, S / 128, Bc), blk, 0, stream>>>(
        q, k, P, nullptr, nullptr, nullptr, nullptr, nullptr,
        S, S, D, scale, SD, SD, SS);
    // 4. rinv[row] = 1/rowsum(P)   (P is L3-resident; k region dead -> holds rinv)
    rowsum_inv<<<dim3(MS), blk, 0, stream>>>(P, rinv, S);
    // 5. att = (P @ vT^T) * rinv   (batched; att overlays q)
    gemm_bt<7, 0, 0><<<dim3(D / 128, S / 128, Bc), blk, 0, stream>>>(
        P, vT, att, nullptr, nullptr, nullptr, nullptr, rinv,
        S, D, S, 1.f, SS, SD, SD);
    // 6. h = relu(att @ Wg1^T + bg1)  (h overlays k/rinv -- rinv consumed)
    gemm_bt<3, 0, 0><<<dim3(D / 128, MS / 128, 1), blk, 0, stream>>>(
        att, Wb + WG1, h, nullptr, Wb + BG1, nullptr, nullptr, nullptr,
        MS, D, D, 1.f, 0, 0, 0);
    // 7. out = sigmoid(sigmoid(h @ Wg2^T + bg2)) * att * ts  (f32 -> d_out)
    gemm_bt<4, 1, 0><<<dim3(D / 128, MS / 128, 1), blk, 0, stream>>>(
        h, Wb + WG2, d_out, nullptr, Wb + BG2, att, Wb + TSO, nullptr,
        MS, D, D, 1.f, 0, 0, 0);
}

// Round 10
// 332.252 us; speedup vs baseline: 1.1612x; 1.0151x over previous
//
#include <hip/hip_runtime.h>

typedef unsigned short ushort_t;
typedef __bf16 bf16x8 __attribute__((ext_vector_type(8)));
typedef float f32x4 __attribute__((ext_vector_type(4)));
typedef short short8 __attribute__((ext_vector_type(8)));

#define SBAR()   asm volatile("s_barrier" ::: "memory")
#define WAITV0() asm volatile("s_waitcnt vmcnt(0)" ::: "memory")
#define WAITV4() asm volatile("s_waitcnt vmcnt(4)" ::: "memory")
#define WAITV8() asm volatile("s_waitcnt vmcnt(8)" ::: "memory")

__device__ __forceinline__ float bf2f(unsigned short u) {
    union { unsigned int i; float f; } v; v.i = ((unsigned int)u) << 16; return v.f;
}
__device__ __forceinline__ unsigned short f2bf(float f) {
    union { float f; unsigned int i; } v; v.f = f;
    unsigned int r = v.i + 0x7fffu + ((v.i >> 16) & 1u);
    return (unsigned short)(r >> 16);
}
__device__ __forceinline__ float sigm(float x) { return 1.0f / (1.0f + __expf(-x)); }

__device__ __forceinline__ void async_copy16(const ushort_t* src, ushort_t* dst_lds) {
    __builtin_amdgcn_global_load_lds(
        (const __attribute__((address_space(1))) void*)src,
        (__attribute__((address_space(3))) void*)dst_lds,
        16, 0, 0);
}

// ---- param conversion: 5 W (768x768) + 5 bias (768) + ts (768), f32 -> bf16 ----
#define WSEG 589824           // 768*768
#define NWALL 2949120         // 5*WSEG
#define NTOT 2953728          // + 6*768
__global__ __launch_bounds__(256)
void convert_params(const float* __restrict__ Wq, const float* __restrict__ Wk,
                    const float* __restrict__ Wv, const float* __restrict__ Wg1,
                    const float* __restrict__ Wg2, const float* __restrict__ bq,
                    const float* __restrict__ bk, const float* __restrict__ bv,
                    const float* __restrict__ bg1, const float* __restrict__ bg2,
                    const float* __restrict__ ts, ushort_t* __restrict__ dst)
{
    int i = (blockIdx.x * 256 + threadIdx.x) * 8;
    if (i >= NTOT) return;
    const float* src; int off;
    if (i < NWALL) {
        int wi = i / WSEG; off = i - wi * WSEG;
        src = (wi == 0) ? Wq : (wi == 1) ? Wk : (wi == 2) ? Wv : (wi == 3) ? Wg1 : Wg2;
    } else {
        int j = i - NWALL; int bi = j / 768; off = j - bi * 768;
        src = (bi == 0) ? bq : (bi == 1) ? bk : (bi == 2) ? bv : (bi == 3) ? bg1 : (bi == 4) ? bg2 : ts;
    }
    float4 a = *(const float4*)(src + off);
    float4 b = *(const float4*)(src + off + 4);
    short8 o;
    o[0] = (short)f2bf(a.x); o[1] = (short)f2bf(a.y); o[2] = (short)f2bf(a.z); o[3] = (short)f2bf(a.w);
    o[4] = (short)f2bf(b.x); o[5] = (short)f2bf(b.y); o[6] = (short)f2bf(b.z); o[7] = (short)f2bf(b.w);
    *(short8*)(dst + i) = o;
}

// ---- input conversion: query/key/value [16384x768] f32 -> bf16 into X[3] ----
#define PERT 12582912ll
__global__ __launch_bounds__(256)
void convert_inputs(const float* __restrict__ q, const float* __restrict__ k,
                    const float* __restrict__ v, ushort_t* __restrict__ X)
{
    long long i = ((long long)blockIdx.x * 256 + threadIdx.x) * 8;
    const float* src; long long off;
    if (i < PERT)          { src = q; off = i; }
    else if (i < 2 * PERT) { src = k; off = i - PERT; }
    else                   { src = v; off = i - 2 * PERT; }
    float4 a = *(const float4*)(src + off);
    float4 b = *(const float4*)(src + off + 4);
    short8 o;
    o[0] = (short)f2bf(a.x); o[1] = (short)f2bf(a.y); o[2] = (short)f2bf(a.z); o[3] = (short)f2bf(a.w);
    o[4] = (short)f2bf(b.x); o[5] = (short)f2bf(b.y); o[6] = (short)f2bf(b.z); o[7] = (short)f2bf(b.w);
    *(short8*)(X + i) = o;
}

// ---- finalize: rinv[row] = 1 / sum_{b<nb} psums[row*nb+b]; rows = grid*256 ----
__global__ __launch_bounds__(256)
void finalize_rinv(const float* __restrict__ psums, float* __restrict__ rinv, int nb)
{
    int row = blockIdx.x * 256 + threadIdx.x;
    const float* p = psums + (size_t)row * nb;
    float s = 0.f;
    for (int i = 0; i < nb; ++i) s += p[i];
    rinv[row] = 1.0f / s;
}

// C[M,N] = A[M,K] @ B[N,K]^T (+ epilogue), optionally batched (M = rows per batch).
// All-bf16 operands via global_load_lds; 3-buffer 2-deep counted-vmcnt pipeline, raw s_barrier.
// CF32: f32 store. QKV: gridDim.z=3; bz selects dest {Cv+bz*batchC | Cv2 for bz==2}, bias+bz*768.
// EPI: 0=plain, 1=+bias, 3=+bias+relu, 4=gate sigmoid(sigmoid(x+bias))*aux*ts,
//      5=exp(x*scale) + per-block row partial sums -> psum_out[bz*M+row][gridDim.x],
//      7=multiply by rinvg[bz*M+row]
// Requires gridDim.x*gridDim.y*gridDim.z % 8 == 0, K%32==0, K>=64.
template<int EPI, int CF32, int QKV>
__global__ __launch_bounds__(256, 2)
void gemm_bt(const ushort_t* __restrict__ A, const ushort_t* __restrict__ B,
             void* __restrict__ Cv, void* __restrict__ Cv2,
             const ushort_t* __restrict__ bias,
             const ushort_t* __restrict__ aux, const ushort_t* __restrict__ ts,
             const float* __restrict__ rinvg, float* __restrict__ psum_out,
             int M, int N, int K, float scale,
             long long batchA, long long batchB, long long batchC)
{
    __shared__ __align__(16) ushort_t As[3][128 * 32];
    __shared__ __align__(16) ushort_t Bs[3][128 * 32];
    __shared__ float rsmx[256];
    const int tid  = threadIdx.x;
    const int lane = tid & 63;
    const int wave = tid >> 6;
    const int wr = wave >> 1, wc = wave & 1;

    // XCD-aware bijective swizzle over the full flat grid (nwg % 8 == 0)
    const int gx = gridDim.x, gy = gridDim.y;
    const int nwg = gx * gy * gridDim.z;
    int fid = (blockIdx.z * gy + blockIdx.y) * gx + blockIdx.x;
    fid = (fid & 7) * (nwg >> 3) + (fid >> 3);
    const int bz  = fid / (gx * gy);
    const int rem = fid - bz * (gx * gy);
    const int by  = rem / gx;
    const int bx  = rem - by * gx;
    const int row0 = by * 128;
    const int col0 = bx * 128;

    f32x4 acc[4][4] = {};

    // staging: 256 threads x 16B = 64 rows of 32 bf16 per inst
    const int srow = tid >> 2;
    const int scol = (tid & 3) * 8;
    const ushort_t* ga0 = A + batchA * bz + (size_t)(row0 + srow) * K + scol;
    const ushort_t* gb0 = B + batchB * bz + (size_t)(col0 + srow) * K + scol;

    const int kop  = (lane >> 4) * 8;
    const int arow = wr * 64 + (lane & 15);
    const int brow = wc * 64 + (lane & 15);

    const int NT = K >> 5;

#define STAGE4(T, BUF) do { const int kk_ = (T) * 32; \
    async_copy16(ga0 + kk_,                  &As[BUF][0] + tid * 8); \
    async_copy16(ga0 + (size_t)64 * K + kk_, &As[BUF][0] + 2048 + tid * 8); \
    async_copy16(gb0 + kk_,                  &Bs[BUF][0] + tid * 8); \
    async_copy16(gb0 + (size_t)64 * K + kk_, &Bs[BUF][0] + 2048 + tid * 8); \
} while (0)

    STAGE4(0, 0);
    STAGE4(1, 1);

    int cur = 0;
    for (int t = 0; t < NT; ++t) {
        if (t + 2 < NT) {
            int nb = cur + 2; if (nb >= 3) nb -= 3;
            STAGE4(t + 2, nb);
            WAITV8();   // tile t landed; tiles t+1, t+2 (8 loads) in flight
        } else if (t + 1 < NT) {
            WAITV4();   // tile t landed; tile t+1 in flight
        } else {
            WAITV0();
        }
        SBAR();
        const ushort_t* Ac = &As[0][0] + cur * 4096;
        const ushort_t* Bc = &Bs[0][0] + cur * 4096;
        bf16x8 af[4], bfr[4];
        #pragma unroll
        for (int m = 0; m < 4; ++m)
            af[m] = *(const bf16x8*)(Ac + (arow + m * 16) * 32 + kop);
        #pragma unroll
        for (int n = 0; n < 4; ++n)
            bfr[n] = *(const bf16x8*)(Bc + (brow + n * 16) * 32 + kop);
        #pragma unroll
        for (int m = 0; m < 4; ++m)
            #pragma unroll
            for (int n = 0; n < 4; ++n)
                acc[m][n] = __builtin_amdgcn_mfma_f32_16x16x32_bf16(af[m], bfr[n], acc[m][n], 0, 0, 0);
        SBAR();
        ++cur; if (cur >= 3) cur = 0;
    }
#undef STAGE4

    // epilogue: C/D layout col=lane&15, row=(lane>>4)*4+reg
    const int r0 = row0 + wr * 64 + (lane >> 4) * 4;
    const int c0 = col0 + wc * 64 + (lane & 15);

    float rv[4][4];
    if (EPI == 7) {
        #pragma unroll
        for (int m = 0; m < 4; ++m)
            #pragma unroll
            for (int r = 0; r < 4; ++r)
                rv[m][r] = rinvg[(size_t)bz * M + r0 + m * 16 + r];
    }
    float rsum[4][4] = {};

    ushort_t* Cb = (QKV && bz == 2) ? (ushort_t*)Cv2 : (ushort_t*)Cv + batchC * bz;
    float* Cf = (float*)Cv;
    #pragma unroll
    for (int m = 0; m < 4; ++m) {
        #pragma unroll
        for (int n = 0; n < 4; ++n) {
            const int col = c0 + n * 16;
            #pragma unroll
            for (int r = 0; r < 4; ++r) {
                const int row = r0 + m * 16 + r;
                float val = acc[m][n][r];
                if (EPI == 1) {
                    val += bf2f(bias[(QKV ? bz * 768 : 0) + col]);
                } else if (EPI == 3) {
                    val += bf2f(bias[col]);
                    val = fmaxf(val, 0.0f);
                } else if (EPI == 4) {
                    val += bf2f(bias[col]);
                    float g  = sigm(val);
                    float gg = sigm(g);
                    val = gg * bf2f(aux[(size_t)row * N + col]) * bf2f(ts[col]);
                } else if (EPI == 5) {
                    val = __expf(val * scale);
                    rsum[m][r] += val;
                } else if (EPI == 7) {
                    val *= rv[m][r];
                }
                if (CF32) Cf[(size_t)row * N + col] = val;
                else      Cb[(size_t)row * N + col] = f2bf(val);
            }
        }
    }

    if (EPI == 5) {
        // reduce over the 16 lanes holding the wave's 16-col groups (lane bits 0..3)
        #pragma unroll
        for (int m = 0; m < 4; ++m)
            #pragma unroll
            for (int r = 0; r < 4; ++r) {
                float s = rsum[m][r];
                s += __shfl_xor(s, 1);
                s += __shfl_xor(s, 2);
                s += __shfl_xor(s, 4);
                s += __shfl_xor(s, 8);
                rsum[m][r] = s;
            }
        if ((lane & 15) == 0) {
            const int quad = lane >> 4;
            #pragma unroll
            for (int m = 0; m < 4; ++m)
                #pragma unroll
                for (int r = 0; r < 4; ++r)
                    rsmx[(wr * 64 + m * 16 + quad * 4 + r) * 2 + wc] = rsum[m][r];
        }
        __syncthreads();
        if (tid < 128) {
            float s = rsmx[tid * 2] + rsmx[tid * 2 + 1];
            psum_out[((size_t)bz * M + row0 + tid) * gx + bx] = s;
        }
    }
}

// VT[z][c][r] = V[z][r][c];  grid (C/32, R/32, Z), block (32,8). bf16.
__global__ __launch_bounds__(256)
void transpose2d(const ushort_t* __restrict__ V, ushort_t* __restrict__ VT, int R, int Ccols)
{
    __shared__ ushort_t t[32][33];
    const size_t zoff = (size_t)blockIdx.z * R * Ccols;
    const int tx = threadIdx.x, ty = threadIdx.y;
    const int c = blockIdx.x * 32 + tx;
    const int rbase = blockIdx.y * 32;
    #pragma unroll
    for (int i = 0; i < 4; ++i)
        t[ty + i * 8][tx] = V[zoff + (size_t)(rbase + ty + i * 8) * Ccols + c];
    __syncthreads();
    const int r = rbase + tx;
    const int cbase = blockIdx.x * 32;
    #pragma unroll
    for (int i = 0; i < 4; ++i)
        VT[zoff + (size_t)(cbase + ty + i * 8) * R + r] = t[tx][ty + i * 8];
}

extern "C" void kernel_launch(void* const* d_in, const int* in_sizes, int n_in,
                              void* d_out, int out_size, void* d_ws, size_t ws_size,
                              hipStream_t stream)
{
    (void)in_sizes; (void)n_in; (void)out_size; (void)ws_size;
    const float* query = (const float*)d_in[0];
    const float* key_  = (const float*)d_in[1];
    const float* value = (const float*)d_in[2];
    const float* Wq  = (const float*)d_in[3];
    const float* bq  = (const float*)d_in[4];
    const float* Wk  = (const float*)d_in[5];
    const float* bk  = (const float*)d_in[6];
    const float* Wv  = (const float*)d_in[7];
    const float* bv  = (const float*)d_in[8];
    const float* Wg1 = (const float*)d_in[9];
    const float* bg1 = (const float*)d_in[10];
    const float* Wg2 = (const float*)d_in[11];
    const float* bg2 = (const float*)d_in[12];
    const float* tsc = (const float*)d_in[13];

    const int S = 2048, D = 768, Bc = 8;
    const int MS = Bc * S;                     // 16384
    const long long SD = (long long)S * D;     // 1,572,864
    const long long SS = (long long)S * S;     // 4,194,304
    const long long MSD = (long long)MS * D;   // 12,582,912

    // ws layout (bytes), total 148,513,792 (proven):
    //   q/att @0 (24MiB) | k/rinv/h @24MiB | vT @48MiB | P @72MiB (64MiB) | Wb @136MiB
    //   X (qkv bf16, 72MiB) @48MiB overlays vT+P (dead before vT/P written)
    //   rinv (64KB) overlays k (k dead after scores; h written only after PV consumed rinv)
    //   psums (2MB f32) parked in d_out (v dead after transpose; d_out rewritten by final GEMM)
    char* ws = (char*)d_ws;
    ushort_t* q    = (ushort_t*)(ws);
    ushort_t* att  = q;                        // PV overwrites q after scores consumed it
    ushort_t* k    = (ushort_t*)(ws + 25165824ll);
    float*    rinv = (float*)(ws + 25165824ll);
    ushort_t* h    = k;
    ushort_t* vT   = (ushort_t*)(ws + 50331648ll);
    ushort_t* X    = (ushort_t*)(ws + 50331648ll);  // 3 x 24MiB
    ushort_t* P    = (ushort_t*)(ws + 75497472ll);
    ushort_t* Wb   = (ushort_t*)(ws + 142606336ll);
    ushort_t* v    = (ushort_t*)d_out;         // bf16 v in front of d_out until transpose
    float*  psums  = (float*)d_out;            // 2MB, alive only between scores and finalize

    const int WQ = 0, WG1 = 1769472, WG2 = 2359296;
    const int BQ = 2949120, BG1 = 2951424, BG2 = 2952192, TSO = 2952960;

    const dim3 blk(256);
    const float scale = 0.03608439182435161f; // 1/sqrt(768)

    // 0. convert params + inputs to bf16
    convert_params<<<dim3((NTOT / 8 + 255) / 256), blk, 0, stream>>>(
        Wq, Wk, Wv, Wg1, Wg2, bq, bk, bv, bg1, bg2, tsc, Wb);
    convert_inputs<<<dim3(18432), blk, 0, stream>>>(query, key_, value, X);
    // 1. fused QKV projections: bz=0->q, 1->k, 2->v (d_out)
    gemm_bt<1, 0, 1><<<dim3(D / 128, MS / 128, 3), blk, 0, stream>>>(
        X, Wb + WQ, q, v, Wb + BQ, nullptr, nullptr, nullptr, nullptr,
        MS, D, D, 1.f, MSD, (long long)WSEG, MSD);
    // 2. vT = transpose(v) per batch; v and X dead afterwards
    transpose2d<<<dim3(D / 32, S / 32, Bc), dim3(32, 8), 0, stream>>>(v, vT, S, D);
    // 3. P = exp(q @ k^T * scale), + per-block row partials -> psums (d_out)
    gemm_bt<5, 0, 0><<<dim3(S / 128, S / 128, Bc), blk, 0, stream>>>(
        q, k, P, nullptr, nullptr, nullptr, nullptr, nullptr, psums,
        S, S, D, scale, SD, SD, SS);
    // 4. rinv[row] = 1/rowsum (16 partials per row; 16384 rows)
    finalize_rinv<<<dim3(MS / 256), blk, 0, stream>>>(psums, rinv, S / 128);
    // 5. att = (P @ vT^T) * rinv   (batched; att overlays q)
    gemm_bt<7, 0, 0><<<dim3(D / 128, S / 128, Bc), blk, 0, stream>>>(
        P, vT, att, nullptr, nullptr, nullptr, nullptr, rinv, nullptr,
        S, D, S, 1.f, SS, SD, SD);
    // 6. h = relu(att @ Wg1^T + bg1)  (h overlays k/rinv -- rinv consumed)
    gemm_bt<3, 0, 0><<<dim3(D / 128, MS / 128, 1), blk, 0, stream>>>(
        att, Wb + WG1, h, nullptr, Wb + BG1, nullptr, nullptr, nullptr, nullptr,
        MS, D, D, 1.f, 0, 0, 0);
    // 7. out = sigmoid(sigmoid(h @ Wg2^T + bg2)) * att * ts  (f32 -> d_out)
    gemm_bt<4, 1, 0><<<dim3(D / 128, MS / 128, 1), blk, 0, stream>>>(
        h, Wb + WG2, d_out, nullptr, Wb + BG2, att, Wb + TSO, nullptr, nullptr,
        MS, D, D, 1.f, 0, 0, 0);
}